// Round 13
// baseline (51.059 us; speedup 1.0000x reference)
//
#include <hip/hip_runtime.h>
#include <math.h>

#define NT 100       // NUM_TOPICS
#define VOCAB 8192
#define TOPN 20
#define CHUNKS 8
#define CCOLS 1024
#define NB (NT * CHUNKS)         // 800 fused blocks
#define CAP 2048
#define NWV 16                   // waves in topk block
#define PRE (NWV * TOPN)         // 320 pre-candidates

// ---------------- node 1: per-topic top-20, wave-parallel extraction ----------------
__global__ __launch_bounds__(1024) void topk_kernel(
    const float* __restrict__ beta,
    int*   __restrict__ top_idx,   // [NT][TOPN]
    float* __restrict__ top_p,     // [NT][TOPN]
    float* __restrict__ rowstats)  // [NT][2] = {rowmax, full sumexp}
{
    const int k = blockIdx.x;
    const int t = threadIdx.x;
    const int wv = t >> 6;         // wave 0..15
    const int lane = t & 63;

    __shared__ float sred[NWV];
    __shared__ int   sredi[NWV];
    __shared__ int   s_base;
    __shared__ float cu[CAP];                // 8 KB candidate values
    __shared__ int   ci[CAP];                // 8 KB candidate global idx
    __shared__ float pv[PRE];                // 1.25 KB pre-selected values
    __shared__ int   pi[PRE];
    __shared__ float s_winv[TOPN];
    __shared__ int   s_wini[TOPN];
    __shared__ float s_ps;

    const float* row = beta + (size_t)k * VOCAB;
    float4 r0 = *reinterpret_cast<const float4*>(row + (size_t)t * 4);
    float4 r1 = *reinterpret_cast<const float4*>(row + (size_t)(1024 + t) * 4);

    // ---- block max ----
    float mx = fmaxf(fmaxf(fmaxf(r0.x, r0.y), fmaxf(r0.z, r0.w)),
                     fmaxf(fmaxf(r1.x, r1.y), fmaxf(r1.z, r1.w)));
#pragma unroll
    for (int off = 32; off >= 1; off >>= 1) mx = fmaxf(mx, __shfl_down(mx, off));
    if (lane == 0) sred[wv] = mx;
    __syncthreads();
    float rowmax = sred[0];
#pragma unroll
    for (int w = 1; w < NWV; ++w) rowmax = fmaxf(rowmax, sred[w]);
    __syncthreads();

    // ---- threshold with count(>=T) >= TOPN (1 iter typical) ----
    float T = rowmax - 2.0f;
    for (int guard = 0; guard < 64; ++guard) {
        int c = 0;
        c += (r0.x >= T) + (r0.y >= T) + (r0.z >= T) + (r0.w >= T);
        c += (r1.x >= T) + (r1.y >= T) + (r1.z >= T) + (r1.w >= T);
#pragma unroll
        for (int off = 32; off >= 1; off >>= 1) c += __shfl_down(c, off);
        if (lane == 0) sredi[wv] = c;
        __syncthreads();
        int cnt = 0;
#pragma unroll
        for (int w = 0; w < NWV; ++w) cnt += sredi[w];
        if (cnt >= TOPN) break;               // uniform decision
        T -= 0.5f;
        __syncthreads();
    }
    if (t == 0) s_base = 0;
    __syncthreads();

    // ---- ballot-compact candidates ----
#pragma unroll
    for (int i = 0; i < 2; ++i) {
        const float4 rr = (i == 0) ? r0 : r1;
#pragma unroll
        for (int e = 0; e < 4; ++e) {
            const float v = (&rr.x)[e];
            const int idx = (i * 1024 + t) * 4 + e;
            const bool pr = (v >= T);
            const unsigned long long mask = __ballot(pr);
            const int pre = __popcll(mask & ((1ull << lane) - 1ull));
            int base = 0;
            if (lane == 0) base = atomicAdd(&s_base, __popcll(mask));
            base = __shfl(base, 0);
            if (pr) {
                const int p = base + pre;
                if (p < CAP) { cu[p] = v; ci[p] = idx; }
            }
        }
    }
    __syncthreads();
    const int ncand = min(s_base, CAP);

    // ---- phase 1: each wave extracts top-20 of its segment (no barriers) ----
    {
        const int seg = (ncand + NWV - 1) / NWV;
        const int lo = wv * seg;
        const int hi = min(lo + seg, ncand);
        for (int it = 0; it < TOPN; ++it) {
            float bv = -INFINITY; int bp = -1;
            for (int p = lo + lane; p < hi; p += 64) {
                const float v = cu[p];
                if (v > bv) { bv = v; bp = p; }
            }
#pragma unroll
            for (int off = 32; off >= 1; off >>= 1) {
                const float ov = __shfl_down(bv, off);
                const int   op = __shfl_down(bp, off);
                if (ov > bv) { bv = ov; bp = op; }
            }
            bp = __shfl(bp, 0);
            bv = __shfl(bv, 0);
            if (lane == 0) {
                pv[wv * TOPN + it] = bv;
                pi[wv * TOPN + it] = (bp >= 0) ? ci[bp] : 0;
            }
            if (bp >= 0) cu[bp] = -INFINITY;   // uniform per-wave write, disjoint segs
        }
    }
    __syncthreads();

    // ---- phase 2: wave 0 extracts final top-20 from 320 pre-candidates ----
    if (wv == 0) {
        for (int it = 0; it < TOPN; ++it) {
            float bv = -INFINITY; int bp = -1;
#pragma unroll
            for (int rp = 0; rp < PRE / 64; ++rp) {
                const int p = rp * 64 + lane;
                const float v = pv[p];
                if (v > bv) { bv = v; bp = p; }
            }
#pragma unroll
            for (int off = 32; off >= 1; off >>= 1) {
                const float ov = __shfl_down(bv, off);
                const int   op = __shfl_down(bp, off);
                if (ov > bv) { bv = ov; bp = op; }
            }
            bp = __shfl(bp, 0);
            bv = __shfl(bv, 0);
            if (lane == 0) { s_winv[it] = bv; s_wini[it] = pi[bp]; }
            pv[bp] = -INFINITY;                // uniform same-addr write
        }
    }
    __syncthreads();

    if (t == 0) {
        float ps = 0.f;
#pragma unroll
        for (int j = 0; j < TOPN; ++j) ps += expf(s_winv[j] - rowmax);
        s_ps = ps;
    }
    __syncthreads();
    if (t < TOPN) {
        top_idx[k * TOPN + t] = s_wini[t];
        top_p[k * TOPN + t]   = expf(s_winv[t] - rowmax) / s_ps;
    }

    // ---- full-row sumexp from registers ----
    float se = expf(r0.x - rowmax) + expf(r0.y - rowmax)
             + expf(r0.z - rowmax) + expf(r0.w - rowmax)
             + expf(r1.x - rowmax) + expf(r1.y - rowmax)
             + expf(r1.z - rowmax) + expf(r1.w - rowmax);
#pragma unroll
    for (int off = 32; off >= 1; off >>= 1) se += __shfl_down(se, off);
    if (lane == 0) sred[wv] = se;
    __syncthreads();
    if (t == 0) {
        float s = 0.f;
#pragma unroll
        for (int w = 0; w < NWV; ++w) s += sred[w];
        rowstats[2 * k + 0] = rowmax;
        rowstats[2 * k + 1] = s;
    }
}

// -------- node 2: fused gather + loss partials (VERBATIM R12, proven) --------
__global__ __launch_bounds__(256) void fused_kernel(
    const float* __restrict__ beta,
    const float* __restrict__ W,
    const int*   __restrict__ top_idx,
    const float* __restrict__ top_p,
    const float* __restrict__ rowstats,
    float* __restrict__ part6)    // [NB][6] = {min,max,Apos,Bpos,Aneg,Bneg}
{
    const int b = blockIdx.x;
    const int k = b / CHUNKS;
    const int c = b % CHUNKS;
    const int t = threadIdx.x;

    __shared__ int   sIdx[TOPN];
    __shared__ float sP[TOPN];
    __shared__ int   cnt[CCOLS];
    __shared__ float sA[4], sB[4], sC[4], sD[4], sE[4], sF[4];

    if (t < TOPN) { sIdx[t] = top_idx[k * TOPN + t]; sP[t] = top_p[k * TOPN + t]; }
#pragma unroll
    for (int i = 0; i < CCOLS / 256; ++i) cnt[i * 256 + t] = 0;
    __syncthreads();

    int   idx_r[TOPN];
    float p_r[TOPN];
#pragma unroll
    for (int j = 0; j < TOPN; ++j) { idx_r[j] = sIdx[j]; p_r[j] = sP[j]; }

    const int lo  = c * CCOLS;
    const int col = lo + t * 4;
    float4 w_r[TOPN];
#pragma unroll
    for (int j = 0; j < TOPN; ++j)
        w_r[j] = *reinterpret_cast<const float4*>(W + (size_t)idx_r[j] * VOCAB + col);
    const float4 bv = *reinterpret_cast<const float4*>(beta + (size_t)k * VOCAB + col);

#pragma unroll 8
    for (int e = t; e < NT * TOPN; e += 256) {
        const int v = top_idx[e] - lo;
        if ((unsigned)v < (unsigned)CCOLS) atomicAdd(&cnt[v], 1);
    }
    __syncthreads();
    if (t < TOPN) {
        const int v = sIdx[t] - lo;
        if ((unsigned)v < (unsigned)CCOLS) atomicSub(&cnt[v], 1);
    }

    float4 m = make_float4(0.f, 0.f, 0.f, 0.f);
#pragma unroll
    for (int j = 0; j < TOPN; ++j) {
        const float pj = p_r[j];
        m.x += pj * w_r[j].x; m.y += pj * w_r[j].y;
        m.z += pj * w_r[j].z; m.w += pj * w_r[j].w;
    }

    float mn  = fminf(fminf(m.x, m.y), fminf(m.z, m.w));
    float mxv = fmaxf(fmaxf(m.x, m.y), fmaxf(m.z, m.w));

    const float rmax = rowstats[2 * k + 0];
    const float rinv = 1.0f / rowstats[2 * k + 1];
    float4 w4;
    w4.x = expf(bv.x - rmax) * rinv;  w4.x = 100.f * w4.x * w4.x;
    w4.y = expf(bv.y - rmax) * rinv;  w4.y = 100.f * w4.y * w4.y;
    w4.z = expf(bv.z - rmax) * rinv;  w4.z = 100.f * w4.z * w4.z;
    w4.w = expf(bv.w - rmax) * rinv;  w4.w = 100.f * w4.w * w4.w;

    __syncthreads();

    float Apos = 0.f, Bpos = 0.f, Aneg = 0.f, Bneg = 0.f;
    {
        const int lc = t * 4;
        if (cnt[lc + 0] > 0) { Apos += w4.x; Bpos += w4.x * m.x; } else { Aneg += w4.x; Bneg += w4.x * m.x; }
        if (cnt[lc + 1] > 0) { Apos += w4.y; Bpos += w4.y * m.y; } else { Aneg += w4.y; Bneg += w4.y * m.y; }
        if (cnt[lc + 2] > 0) { Apos += w4.z; Bpos += w4.z * m.z; } else { Aneg += w4.z; Bneg += w4.z * m.z; }
        if (cnt[lc + 3] > 0) { Apos += w4.w; Bpos += w4.w * m.w; } else { Aneg += w4.w; Bneg += w4.w * m.w; }
    }

#pragma unroll
    for (int off = 32; off >= 1; off >>= 1) {
        mn   = fminf(mn,  __shfl_down(mn,  off));
        mxv  = fmaxf(mxv, __shfl_down(mxv, off));
        Apos += __shfl_down(Apos, off);
        Bpos += __shfl_down(Bpos, off);
        Aneg += __shfl_down(Aneg, off);
        Bneg += __shfl_down(Bneg, off);
    }
    if ((t & 63) == 0) {
        const int w = t >> 6;
        sA[w] = mn; sB[w] = mxv; sC[w] = Apos; sD[w] = Bpos; sE[w] = Aneg; sF[w] = Bneg;
    }
    __syncthreads();
    if (t == 0) {
        part6[b * 6 + 0] = fminf(fminf(sA[0], sA[1]), fminf(sA[2], sA[3]));
        part6[b * 6 + 1] = fmaxf(fmaxf(sB[0], sB[1]), fmaxf(sB[2], sB[3]));
        part6[b * 6 + 2] = sC[0] + sC[1] + sC[2] + sC[3];
        part6[b * 6 + 3] = sD[0] + sD[1] + sD[2] + sD[3];
        part6[b * 6 + 4] = sE[0] + sE[1] + sE[2] + sE[3];
        part6[b * 6 + 5] = sF[0] + sF[1] + sF[2] + sF[3];
    }
}

// ---------------- node 3: deterministic finalize (VERBATIM R12) ----------------
__global__ __launch_bounds__(128) void finalize_kernel(
    const float* __restrict__ part6,
    const int*   __restrict__ epoch,
    float* __restrict__ out)
{
    const int t = threadIdx.x;
    __shared__ float sp[128], sn[128];
    float pos = 0.f, neg = 0.f;
    if (t < NT) {
        float mn = INFINITY, mxv = -INFINITY;
        float Ap = 0.f, Bp = 0.f, An = 0.f, Bn = 0.f;
        for (int cc = 0; cc < CHUNKS; ++cc) {
            const float* p6 = part6 + (size_t)(t * CHUNKS + cc) * 6;
            mn  = fminf(mn,  p6[0]);
            mxv = fmaxf(mxv, p6[1]);
            Ap += p6[2]; Bp += p6[3]; An += p6[4]; Bn += p6[5];
        }
        const float inv = 1.0f / (mxv - mn);
        pos = Ap - inv * (Bp - mn * Ap);
        neg = An - inv * (Bn - mn * An);
    }
    sp[t] = pos; sn[t] = neg;
    __syncthreads();
    if (t == 0) {
        float P = 0.f, N = 0.f;
        for (int i = 0; i < NT; ++i) { P += sp[i]; N += sn[i]; }
        const float total = (P * 0.7f + N * 0.3f) * 2.0f;
        const int e = *epoch;
        const float la = (e < 100) ? (float)e : 100.0f;
        *out = la * total;
    }
}

extern "C" void kernel_launch(void* const* d_in, const int* in_sizes, int n_in,
                              void* d_out, int out_size, void* d_ws, size_t ws_size,
                              hipStream_t stream)
{
    (void)in_sizes; (void)n_in; (void)out_size; (void)ws_size;
    const float* beta  = (const float*)d_in[0];
    const float* W     = (const float*)d_in[1];
    const int*   epoch = (const int*)d_in[2];
    float* out = (float*)d_out;

    char* ws = (char*)d_ws;
    int*   top_idx  = (int*)ws;    ws += NT * TOPN * sizeof(int);
    float* top_p    = (float*)ws;  ws += NT * TOPN * sizeof(float);
    float* rowstats = (float*)ws;  ws += NT * 2 * sizeof(float);
    float* part6    = (float*)ws;  ws += NB * 6 * sizeof(float);

    topk_kernel<<<NT, 1024, 0, stream>>>(beta, top_idx, top_p, rowstats);
    fused_kernel<<<NB, 256, 0, stream>>>(beta, W, top_idx, top_p, rowstats, part6);
    finalize_kernel<<<1, 128, 0, stream>>>(part6, epoch, out);
}

// Round 14
// 49.950 us; speedup vs baseline: 1.0222x; 1.0222x over previous
//
#include <hip/hip_runtime.h>
#include <math.h>

#define NT 100       // NUM_TOPICS
#define VOCAB 8192
#define TOPN 20
#define NSL 4        // slices per topic
#define SCOLS 2048   // cols per slice
#define SCAP 256     // candidate slots per slice
#define CHUNKS 8
#define CCOLS 1024
#define NB (NT * CHUNKS)         // 800 fused blocks

// ---------- node 1: per-(topic,slice) stats + threshold candidate dump ----------
__global__ __launch_bounds__(256) void slice_kernel(
    const float* __restrict__ beta,
    float* __restrict__ cand_val,   // [NT*NSL][SCAP]
    int*   __restrict__ cand_idx,   // [NT*NSL][SCAP]
    int*   __restrict__ sl_cnt,     // [NT*NSL]
    float* __restrict__ sl_max,     // [NT*NSL]
    float* __restrict__ sl_sum)     // [NT*NSL]
{
    const int b = blockIdx.x;
    const int t = threadIdx.x;
    const int k = b / NSL;
    const int s = b % NSL;
    const int col0 = s * SCOLS;

    __shared__ float sred[4];
    __shared__ int   sredi[4];
    __shared__ int   s_cnt;

    const float* base = beta + (size_t)k * VOCAB + col0;
    const float4 v0 = *reinterpret_cast<const float4*>(base + t * 4);
    const float4 v1 = *reinterpret_cast<const float4*>(base + 1024 + t * 4);

    // slice max
    float mx = fmaxf(fmaxf(fmaxf(v0.x, v0.y), fmaxf(v0.z, v0.w)),
                     fmaxf(fmaxf(v1.x, v1.y), fmaxf(v1.z, v1.w)));
#pragma unroll
    for (int off = 32; off >= 1; off >>= 1) mx = fmaxf(mx, __shfl_down(mx, off));
    if ((t & 63) == 0) sred[t >> 6] = mx;
    __syncthreads();
    const float smax = fmaxf(fmaxf(sred[0], sred[1]), fmaxf(sred[2], sred[3]));
    __syncthreads();

    // slice sumexp (local max)
    float se = expf(v0.x - smax) + expf(v0.y - smax) + expf(v0.z - smax) + expf(v0.w - smax)
             + expf(v1.x - smax) + expf(v1.y - smax) + expf(v1.z - smax) + expf(v1.w - smax);
#pragma unroll
    for (int off = 32; off >= 1; off >>= 1) se += __shfl_down(se, off);
    if ((t & 63) == 0) sred[t >> 6] = se;
    __syncthreads();
    const float ssum = sred[0] + sred[1] + sred[2] + sred[3];
    __syncthreads();

    // threshold with slice count >= TOPN
    float T = smax - 1.5f;
    for (int g = 0; g < 16; ++g) {
        int c = ((v0.x >= T) ? 1 : 0) + ((v0.y >= T) ? 1 : 0)
              + ((v0.z >= T) ? 1 : 0) + ((v0.w >= T) ? 1 : 0)
              + ((v1.x >= T) ? 1 : 0) + ((v1.y >= T) ? 1 : 0)
              + ((v1.z >= T) ? 1 : 0) + ((v1.w >= T) ? 1 : 0);
#pragma unroll
        for (int off = 32; off >= 1; off >>= 1) c += __shfl_down(c, off);
        if ((t & 63) == 0) sredi[t >> 6] = c;
        __syncthreads();
        const int cnt = sredi[0] + sredi[1] + sredi[2] + sredi[3];
        if (cnt >= TOPN) break;              // uniform decision
        T -= 0.4f;
        __syncthreads();
    }
    if (t == 0) s_cnt = 0;
    __syncthreads();

    // ballot-compact candidates into block-owned region
#pragma unroll
    for (int i = 0; i < 2; ++i) {
        const float4 rr = (i == 0) ? v0 : v1;
#pragma unroll
        for (int e = 0; e < 4; ++e) {
            const float val = (&rr.x)[e];
            const bool  pr  = (val >= T);
            const unsigned long long mask = __ballot(pr);
            const int lane = t & 63;
            const int pre  = __popcll(mask & ((1ull << lane) - 1ull));
            int bs = 0;
            if (lane == 0) bs = atomicAdd(&s_cnt, __popcll(mask));
            bs = __shfl(bs, 0);
            if (pr) {
                const int p = bs + pre;
                if (p < SCAP) {
                    cand_val[(size_t)b * SCAP + p] = val;
                    cand_idx[(size_t)b * SCAP + p] = col0 + i * 1024 + t * 4 + e;
                }
            }
        }
    }
    __syncthreads();
    if (t == 0) {
        sl_cnt[b] = min(s_cnt, SCAP);
        sl_max[b] = smax;
        sl_sum[b] = ssum;
    }
}

// ---------- node 2: per-topic merge, 4-wave-parallel extraction ----------
__global__ __launch_bounds__(256) void merge_kernel(
    const float* __restrict__ cand_val,
    const int*   __restrict__ cand_idx,
    const int*   __restrict__ sl_cnt,
    const float* __restrict__ sl_max,
    const float* __restrict__ sl_sum,
    int*   __restrict__ top_idx,    // [NT][TOPN]
    float* __restrict__ top_p,      // [NT][TOPN]
    float* __restrict__ rowstats)   // [NT][2]
{
    const int k = blockIdx.x;
    const int t = threadIdx.x;
    const int wv = t >> 6;          // wave 0..3 <-> slice 0..3
    const int lane = t & 63;

    __shared__ float cu[NSL * SCAP];         // 4 KB
    __shared__ int   cid[NSL * SCAP];        // 4 KB
    __shared__ int   scnt[NSL];
    __shared__ float smaxs[NSL], ssums[NSL];
    __shared__ float pv[NSL * TOPN];         // 80 pre-candidates
    __shared__ int   pid[NSL * TOPN];
    __shared__ float s_winv[TOPN];
    __shared__ int   s_wini[TOPN];
    __shared__ float s_ps;

    if (t < NSL) {
        scnt[t]  = sl_cnt[k * NSL + t];
        smaxs[t] = sl_max[k * NSL + t];
        ssums[t] = sl_sum[k * NSL + t];
    }
    __syncthreads();

    // wave w stages + extracts top-20 of its own slice (wave-local, no barriers)
    {
        const int n = scnt[wv];
        const size_t gbase = (size_t)(k * NSL + wv) * SCAP;
        for (int p = lane; p < n; p += 64) {
            cu[wv * SCAP + p]  = cand_val[gbase + p];
            cid[wv * SCAP + p] = cand_idx[gbase + p];
        }
        // wave-internal visibility of LDS writes is in-order per lane; cross-lane
        // reads below only occur after the wave-wide argmax loop touches all p,
        // which the same lanes wrote. (ds ops from the same wave are ordered.)
        for (int it = 0; it < TOPN; ++it) {
            float bv = -INFINITY; int bp = -1;
            for (int p = lane; p < n; p += 64) {
                const float v = cu[wv * SCAP + p];
                if (v > bv) { bv = v; bp = p; }
            }
#pragma unroll
            for (int off = 32; off >= 1; off >>= 1) {
                const float ov = __shfl_down(bv, off);
                const int   op = __shfl_down(bp, off);
                if (ov > bv) { bv = ov; bp = op; }
            }
            bp = __shfl(bp, 0);
            bv = __shfl(bv, 0);
            if (lane == 0) {
                pv[wv * TOPN + it]  = bv;
                pid[wv * TOPN + it] = (bp >= 0) ? cid[wv * SCAP + bp] : 0;
            }
            if (bp >= 0) cu[wv * SCAP + bp] = -INFINITY;  // uniform wave write
        }
    }
    __syncthreads();

    // wave 0: final top-20 over 80 pre-candidates
    if (wv == 0) {
        for (int it = 0; it < TOPN; ++it) {
            float bv = -INFINITY; int bp = -1;
            for (int p = lane; p < NSL * TOPN; p += 64) {
                const float v = pv[p];
                if (v > bv) { bv = v; bp = p; }
            }
#pragma unroll
            for (int off = 32; off >= 1; off >>= 1) {
                const float ov = __shfl_down(bv, off);
                const int   op = __shfl_down(bp, off);
                if (ov > bv) { bv = ov; bp = op; }
            }
            bp = __shfl(bp, 0);
            bv = __shfl(bv, 0);
            if (lane == 0) { s_winv[it] = bv; s_wini[it] = pid[bp]; }
            pv[bp] = -INFINITY;              // uniform same-addr write
        }
    }
    __syncthreads();

    if (t == 0) {
        const float rowmax = s_winv[0];
        float ps = 0.f;
#pragma unroll
        for (int j = 0; j < TOPN; ++j) ps += expf(s_winv[j] - rowmax);
        s_ps = ps;
        float rs = 0.f;
#pragma unroll
        for (int s = 0; s < NSL; ++s) rs += ssums[s] * expf(smaxs[s] - rowmax);
        rowstats[2 * k + 0] = rowmax;
        rowstats[2 * k + 1] = rs;
    }
    __syncthreads();
    if (t < TOPN) {
        top_idx[k * TOPN + t] = s_wini[t];
        top_p[k * TOPN + t]   = expf(s_winv[t] - s_winv[0]) / s_ps;
    }
}

// -------- node 3: fused gather + loss partials (VERBATIM R12, proven) --------
__global__ __launch_bounds__(256) void fused_kernel(
    const float* __restrict__ beta,
    const float* __restrict__ W,
    const int*   __restrict__ top_idx,
    const float* __restrict__ top_p,
    const float* __restrict__ rowstats,
    float* __restrict__ part6)    // [NB][6]
{
    const int b = blockIdx.x;
    const int k = b / CHUNKS;
    const int c = b % CHUNKS;
    const int t = threadIdx.x;

    __shared__ int   sIdx[TOPN];
    __shared__ float sP[TOPN];
    __shared__ int   cnt[CCOLS];
    __shared__ float sA[4], sB[4], sC[4], sD[4], sE[4], sF[4];

    if (t < TOPN) { sIdx[t] = top_idx[k * TOPN + t]; sP[t] = top_p[k * TOPN + t]; }
#pragma unroll
    for (int i = 0; i < CCOLS / 256; ++i) cnt[i * 256 + t] = 0;
    __syncthreads();

    int   idx_r[TOPN];
    float p_r[TOPN];
#pragma unroll
    for (int j = 0; j < TOPN; ++j) { idx_r[j] = sIdx[j]; p_r[j] = sP[j]; }

    const int lo  = c * CCOLS;
    const int col = lo + t * 4;
    float4 w_r[TOPN];
#pragma unroll
    for (int j = 0; j < TOPN; ++j)
        w_r[j] = *reinterpret_cast<const float4*>(W + (size_t)idx_r[j] * VOCAB + col);
    const float4 bv = *reinterpret_cast<const float4*>(beta + (size_t)k * VOCAB + col);

#pragma unroll 8
    for (int e = t; e < NT * TOPN; e += 256) {
        const int v = top_idx[e] - lo;
        if ((unsigned)v < (unsigned)CCOLS) atomicAdd(&cnt[v], 1);
    }
    __syncthreads();
    if (t < TOPN) {
        const int v = sIdx[t] - lo;
        if ((unsigned)v < (unsigned)CCOLS) atomicSub(&cnt[v], 1);
    }

    float4 m = make_float4(0.f, 0.f, 0.f, 0.f);
#pragma unroll
    for (int j = 0; j < TOPN; ++j) {
        const float pj = p_r[j];
        m.x += pj * w_r[j].x; m.y += pj * w_r[j].y;
        m.z += pj * w_r[j].z; m.w += pj * w_r[j].w;
    }

    float mn  = fminf(fminf(m.x, m.y), fminf(m.z, m.w));
    float mxv = fmaxf(fmaxf(m.x, m.y), fmaxf(m.z, m.w));

    const float rmax = rowstats[2 * k + 0];
    const float rinv = 1.0f / rowstats[2 * k + 1];
    float4 w4;
    w4.x = expf(bv.x - rmax) * rinv;  w4.x = 100.f * w4.x * w4.x;
    w4.y = expf(bv.y - rmax) * rinv;  w4.y = 100.f * w4.y * w4.y;
    w4.z = expf(bv.z - rmax) * rinv;  w4.z = 100.f * w4.z * w4.z;
    w4.w = expf(bv.w - rmax) * rinv;  w4.w = 100.f * w4.w * w4.w;

    __syncthreads();

    float Apos = 0.f, Bpos = 0.f, Aneg = 0.f, Bneg = 0.f;
    {
        const int lc = t * 4;
        if (cnt[lc + 0] > 0) { Apos += w4.x; Bpos += w4.x * m.x; } else { Aneg += w4.x; Bneg += w4.x * m.x; }
        if (cnt[lc + 1] > 0) { Apos += w4.y; Bpos += w4.y * m.y; } else { Aneg += w4.y; Bneg += w4.y * m.y; }
        if (cnt[lc + 2] > 0) { Apos += w4.z; Bpos += w4.z * m.z; } else { Aneg += w4.z; Bneg += w4.z * m.z; }
        if (cnt[lc + 3] > 0) { Apos += w4.w; Bpos += w4.w * m.w; } else { Aneg += w4.w; Bneg += w4.w * m.w; }
    }

#pragma unroll
    for (int off = 32; off >= 1; off >>= 1) {
        mn   = fminf(mn,  __shfl_down(mn,  off));
        mxv  = fmaxf(mxv, __shfl_down(mxv, off));
        Apos += __shfl_down(Apos, off);
        Bpos += __shfl_down(Bpos, off);
        Aneg += __shfl_down(Aneg, off);
        Bneg += __shfl_down(Bneg, off);
    }
    if ((t & 63) == 0) {
        const int w = t >> 6;
        sA[w] = mn; sB[w] = mxv; sC[w] = Apos; sD[w] = Bpos; sE[w] = Aneg; sF[w] = Bneg;
    }
    __syncthreads();
    if (t == 0) {
        part6[b * 6 + 0] = fminf(fminf(sA[0], sA[1]), fminf(sA[2], sA[3]));
        part6[b * 6 + 1] = fmaxf(fmaxf(sB[0], sB[1]), fmaxf(sB[2], sB[3]));
        part6[b * 6 + 2] = sC[0] + sC[1] + sC[2] + sC[3];
        part6[b * 6 + 3] = sD[0] + sD[1] + sD[2] + sD[3];
        part6[b * 6 + 4] = sE[0] + sE[1] + sE[2] + sE[3];
        part6[b * 6 + 5] = sF[0] + sF[1] + sF[2] + sF[3];
    }
}

// ---------------- node 4: deterministic finalize (VERBATIM R12) ----------------
__global__ __launch_bounds__(128) void finalize_kernel(
    const float* __restrict__ part6,
    const int*   __restrict__ epoch,
    float* __restrict__ out)
{
    const int t = threadIdx.x;
    __shared__ float sp[128], sn[128];
    float pos = 0.f, neg = 0.f;
    if (t < NT) {
        float mn = INFINITY, mxv = -INFINITY;
        float Ap = 0.f, Bp = 0.f, An = 0.f, Bn = 0.f;
        for (int cc = 0; cc < CHUNKS; ++cc) {
            const float* p6 = part6 + (size_t)(t * CHUNKS + cc) * 6;
            mn  = fminf(mn,  p6[0]);
            mxv = fmaxf(mxv, p6[1]);
            Ap += p6[2]; Bp += p6[3]; An += p6[4]; Bn += p6[5];
        }
        const float inv = 1.0f / (mxv - mn);
        pos = Ap - inv * (Bp - mn * Ap);
        neg = An - inv * (Bn - mn * An);
    }
    sp[t] = pos; sn[t] = neg;
    __syncthreads();
    if (t == 0) {
        float P = 0.f, N = 0.f;
        for (int i = 0; i < NT; ++i) { P += sp[i]; N += sn[i]; }
        const float total = (P * 0.7f + N * 0.3f) * 2.0f;
        const int e = *epoch;
        const float la = (e < 100) ? (float)e : 100.0f;
        *out = la * total;
    }
}

extern "C" void kernel_launch(void* const* d_in, const int* in_sizes, int n_in,
                              void* d_out, int out_size, void* d_ws, size_t ws_size,
                              hipStream_t stream)
{
    (void)in_sizes; (void)n_in; (void)out_size; (void)ws_size;
    const float* beta  = (const float*)d_in[0];
    const float* W     = (const float*)d_in[1];
    const int*   epoch = (const int*)d_in[2];
    float* out = (float*)d_out;

    char* ws = (char*)d_ws;
    float* cand_val = (float*)ws;  ws += (size_t)NT * NSL * SCAP * sizeof(float);
    int*   cand_idx = (int*)ws;    ws += (size_t)NT * NSL * SCAP * sizeof(int);
    int*   sl_cnt   = (int*)ws;    ws += NT * NSL * sizeof(int);
    float* sl_max   = (float*)ws;  ws += NT * NSL * sizeof(float);
    float* sl_sum   = (float*)ws;  ws += NT * NSL * sizeof(float);
    int*   top_idx  = (int*)ws;    ws += NT * TOPN * sizeof(int);
    float* top_p    = (float*)ws;  ws += NT * TOPN * sizeof(float);
    float* rowstats = (float*)ws;  ws += NT * 2 * sizeof(float);
    float* part6    = (float*)ws;  ws += NB * 6 * sizeof(float);

    slice_kernel<<<NT * NSL, 256, 0, stream>>>(beta, cand_val, cand_idx,
                                               sl_cnt, sl_max, sl_sum);
    merge_kernel<<<NT, 256, 0, stream>>>(cand_val, cand_idx, sl_cnt, sl_max, sl_sum,
                                         top_idx, top_p, rowstats);
    fused_kernel<<<NB, 256, 0, stream>>>(beta, W, top_idx, top_p, rowstats, part6);
    finalize_kernel<<<1, 128, 0, stream>>>(part6, epoch, out);
}

// Round 15
// 47.085 us; speedup vs baseline: 1.0844x; 1.0609x over previous
//
#include <hip/hip_runtime.h>
#include <math.h>

#define NT 100       // NUM_TOPICS
#define VOCAB 8192
#define TOPN 20
#define NWV 4        // waves per topk block
#define WCOLS 2048   // cols per wave
#define SCAP 256     // wave-private candidate capacity
#define CHUNKS 8
#define CCOLS 1024
#define NB (NT * CHUNKS)         // 800 fused blocks

// ---- node 1: per-topic top-20, all phases wave-local, 1 block barrier ----
__global__ __launch_bounds__(256) void topk_kernel(
    const float* __restrict__ beta,
    int*   __restrict__ top_idx,   // [NT][TOPN]
    float* __restrict__ top_p,     // [NT][TOPN]
    float* __restrict__ rowstats)  // [NT][2] = {rowmax, full sumexp}
{
    const int k = blockIdx.x;
    const int t = threadIdx.x;
    const int wv = t >> 6;          // wave 0..3
    const int lane = t & 63;

    __shared__ float cu[NWV * SCAP];        // 4 KB wave-private candidates
    __shared__ int   cid[NWV * SCAP];       // 4 KB
    __shared__ float smaxs[NWV], ssums[NWV];
    __shared__ float pv[NWV * TOPN];        // 80 pre-candidates
    __shared__ int   pid[NWV * TOPN];
    __shared__ float s_winv[TOPN];
    __shared__ int   s_wini[TOPN];
    __shared__ float s_ps, s_rowmax;

    // ---- wave-local load: 8 float4 = 32 cols/lane ----
    const float* base = beta + (size_t)k * VOCAB + wv * WCOLS;
    float4 r[8];
    float mx = -INFINITY;
#pragma unroll
    for (int i = 0; i < 8; ++i) {
        r[i] = *reinterpret_cast<const float4*>(base + (size_t)(i * 64 + lane) * 4);
        mx = fmaxf(mx, fmaxf(fmaxf(r[i].x, r[i].y), fmaxf(r[i].z, r[i].w)));
    }
    // wave max (butterfly so all lanes hold it)
#pragma unroll
    for (int off = 32; off >= 1; off >>= 1) mx = fmaxf(mx, __shfl_xor(mx, off));
    const float smax = mx;

    // ---- wave-local sumexp ----
    float se = 0.f;
#pragma unroll
    for (int i = 0; i < 8; ++i) {
        se += expf(r[i].x - smax) + expf(r[i].y - smax)
            + expf(r[i].z - smax) + expf(r[i].w - smax);
    }
#pragma unroll
    for (int off = 32; off >= 1; off >>= 1) se += __shfl_xor(se, off);
    const float ssum = se;

    if (lane == 0) { smaxs[wv] = smax; ssums[wv] = ssum; }

    // ---- wave-local threshold: count(>=T) >= TOPN within this wave's slice ----
    float T = smax - 1.5f;
    for (int g = 0; g < 16; ++g) {
        int c = 0;
#pragma unroll
        for (int i = 0; i < 8; ++i) {
            c += (r[i].x >= T) + (r[i].y >= T) + (r[i].z >= T) + (r[i].w >= T);
        }
#pragma unroll
        for (int off = 32; off >= 1; off >>= 1) c += __shfl_xor(c, off);
        if (c >= TOPN) break;               // wave-uniform decision
        T -= 0.4f;
    }

    // ---- wave-local ballot-compact into wave-private LDS segment ----
    int wbase = 0;
#pragma unroll
    for (int i = 0; i < 8; ++i) {
#pragma unroll
        for (int e = 0; e < 4; ++e) {
            const float v = (&r[i].x)[e];
            const bool pr = (v >= T);
            const unsigned long long mask = __ballot(pr);
            const int pre = __popcll(mask & ((1ull << lane) - 1ull));
            if (pr) {
                const int p = wbase + pre;
                if (p < SCAP) {
                    cu[wv * SCAP + p]  = v;
                    cid[wv * SCAP + p] = wv * WCOLS + (i * 64 + lane) * 4 + e;
                }
            }
            wbase += __popcll(mask);        // wave-uniform
        }
    }
    const int n = min(wbase, SCAP);

    // ---- wave-local top-20 extraction over own candidates ----
    for (int it = 0; it < TOPN; ++it) {
        float bv = -INFINITY; int bp = -1;
        for (int p = lane; p < n; p += 64) {
            const float v = cu[wv * SCAP + p];
            if (v > bv) { bv = v; bp = p; }
        }
#pragma unroll
        for (int off = 32; off >= 1; off >>= 1) {
            const float ov = __shfl_down(bv, off);
            const int   op = __shfl_down(bp, off);
            if (ov > bv) { bv = ov; bp = op; }
        }
        bp = __shfl(bp, 0);
        bv = __shfl(bv, 0);
        if (lane == 0) {
            pv[wv * TOPN + it]  = bv;
            pid[wv * TOPN + it] = (bp >= 0) ? cid[wv * SCAP + bp] : 0;
        }
        if (bp >= 0) cu[wv * SCAP + bp] = -INFINITY;   // wave-uniform write
    }
    __syncthreads();                         // the ONLY pre-merge block barrier

    // ---- wave 0: final top-20 over 80 pre-candidates ----
    if (wv == 0) {
        for (int it = 0; it < TOPN; ++it) {
            float bv = -INFINITY; int bp = -1;
            for (int p = lane; p < NWV * TOPN; p += 64) {
                const float v = pv[p];
                if (v > bv) { bv = v; bp = p; }
            }
#pragma unroll
            for (int off = 32; off >= 1; off >>= 1) {
                const float ov = __shfl_down(bv, off);
                const int   op = __shfl_down(bp, off);
                if (ov > bv) { bv = ov; bp = op; }
            }
            bp = __shfl(bp, 0);
            bv = __shfl(bv, 0);
            if (lane == 0) { s_winv[it] = bv; s_wini[it] = pid[bp]; }
            pv[bp] = -INFINITY;              // uniform same-addr write
        }
        if (lane == 0) {
            const float rowmax = s_winv[0];  // global row max = top candidate
            float ps = 0.f;
#pragma unroll
            for (int j = 0; j < TOPN; ++j) ps += expf(s_winv[j] - rowmax);
            float rs = 0.f;
#pragma unroll
            for (int s = 0; s < NWV; ++s) rs += ssums[s] * expf(smaxs[s] - rowmax);
            s_rowmax = rowmax;
            s_ps = ps;
            rowstats[2 * k + 0] = rowmax;
            rowstats[2 * k + 1] = rs;
        }
    }
    __syncthreads();
    if (t < TOPN) {
        top_idx[k * TOPN + t] = s_wini[t];
        top_p[k * TOPN + t]   = expf(s_winv[t] - s_rowmax) / s_ps;
    }
}

// -------- node 2: fused gather + loss partials (VERBATIM R12, proven) --------
__global__ __launch_bounds__(256) void fused_kernel(
    const float* __restrict__ beta,
    const float* __restrict__ W,
    const int*   __restrict__ top_idx,
    const float* __restrict__ top_p,
    const float* __restrict__ rowstats,
    float* __restrict__ part6)    // [NB][6]
{
    const int b = blockIdx.x;
    const int k = b / CHUNKS;
    const int c = b % CHUNKS;
    const int t = threadIdx.x;

    __shared__ int   sIdx[TOPN];
    __shared__ float sP[TOPN];
    __shared__ int   cnt[CCOLS];
    __shared__ float sA[4], sB[4], sC[4], sD[4], sE[4], sF[4];

    if (t < TOPN) { sIdx[t] = top_idx[k * TOPN + t]; sP[t] = top_p[k * TOPN + t]; }
#pragma unroll
    for (int i = 0; i < CCOLS / 256; ++i) cnt[i * 256 + t] = 0;
    __syncthreads();

    int   idx_r[TOPN];
    float p_r[TOPN];
#pragma unroll
    for (int j = 0; j < TOPN; ++j) { idx_r[j] = sIdx[j]; p_r[j] = sP[j]; }

    const int lo  = c * CCOLS;
    const int col = lo + t * 4;
    float4 w_r[TOPN];
#pragma unroll
    for (int j = 0; j < TOPN; ++j)
        w_r[j] = *reinterpret_cast<const float4*>(W + (size_t)idx_r[j] * VOCAB + col);
    const float4 bv = *reinterpret_cast<const float4*>(beta + (size_t)k * VOCAB + col);

#pragma unroll 8
    for (int e = t; e < NT * TOPN; e += 256) {
        const int v = top_idx[e] - lo;
        if ((unsigned)v < (unsigned)CCOLS) atomicAdd(&cnt[v], 1);
    }
    __syncthreads();
    if (t < TOPN) {
        const int v = sIdx[t] - lo;
        if ((unsigned)v < (unsigned)CCOLS) atomicSub(&cnt[v], 1);
    }

    float4 m = make_float4(0.f, 0.f, 0.f, 0.f);
#pragma unroll
    for (int j = 0; j < TOPN; ++j) {
        const float pj = p_r[j];
        m.x += pj * w_r[j].x; m.y += pj * w_r[j].y;
        m.z += pj * w_r[j].z; m.w += pj * w_r[j].w;
    }

    float mn  = fminf(fminf(m.x, m.y), fminf(m.z, m.w));
    float mxv = fmaxf(fmaxf(m.x, m.y), fmaxf(m.z, m.w));

    const float rmax = rowstats[2 * k + 0];
    const float rinv = 1.0f / rowstats[2 * k + 1];
    float4 w4;
    w4.x = expf(bv.x - rmax) * rinv;  w4.x = 100.f * w4.x * w4.x;
    w4.y = expf(bv.y - rmax) * rinv;  w4.y = 100.f * w4.y * w4.y;
    w4.z = expf(bv.z - rmax) * rinv;  w4.z = 100.f * w4.z * w4.z;
    w4.w = expf(bv.w - rmax) * rinv;  w4.w = 100.f * w4.w * w4.w;

    __syncthreads();

    float Apos = 0.f, Bpos = 0.f, Aneg = 0.f, Bneg = 0.f;
    {
        const int lc = t * 4;
        if (cnt[lc + 0] > 0) { Apos += w4.x; Bpos += w4.x * m.x; } else { Aneg += w4.x; Bneg += w4.x * m.x; }
        if (cnt[lc + 1] > 0) { Apos += w4.y; Bpos += w4.y * m.y; } else { Aneg += w4.y; Bneg += w4.y * m.y; }
        if (cnt[lc + 2] > 0) { Apos += w4.z; Bpos += w4.z * m.z; } else { Aneg += w4.z; Bneg += w4.z * m.z; }
        if (cnt[lc + 3] > 0) { Apos += w4.w; Bpos += w4.w * m.w; } else { Aneg += w4.w; Bneg += w4.w * m.w; }
    }

#pragma unroll
    for (int off = 32; off >= 1; off >>= 1) {
        mn   = fminf(mn,  __shfl_down(mn,  off));
        mxv  = fmaxf(mxv, __shfl_down(mxv, off));
        Apos += __shfl_down(Apos, off);
        Bpos += __shfl_down(Bpos, off);
        Aneg += __shfl_down(Aneg, off);
        Bneg += __shfl_down(Bneg, off);
    }
    if ((t & 63) == 0) {
        const int w = t >> 6;
        sA[w] = mn; sB[w] = mxv; sC[w] = Apos; sD[w] = Bpos; sE[w] = Aneg; sF[w] = Bneg;
    }
    __syncthreads();
    if (t == 0) {
        part6[b * 6 + 0] = fminf(fminf(sA[0], sA[1]), fminf(sA[2], sA[3]));
        part6[b * 6 + 1] = fmaxf(fmaxf(sB[0], sB[1]), fmaxf(sB[2], sB[3]));
        part6[b * 6 + 2] = sC[0] + sC[1] + sC[2] + sC[3];
        part6[b * 6 + 3] = sD[0] + sD[1] + sD[2] + sD[3];
        part6[b * 6 + 4] = sE[0] + sE[1] + sE[2] + sE[3];
        part6[b * 6 + 5] = sF[0] + sF[1] + sF[2] + sF[3];
    }
}

// ---------------- node 3: deterministic finalize (VERBATIM R12) ----------------
__global__ __launch_bounds__(128) void finalize_kernel(
    const float* __restrict__ part6,
    const int*   __restrict__ epoch,
    float* __restrict__ out)
{
    const int t = threadIdx.x;
    __shared__ float sp[128], sn[128];
    float pos = 0.f, neg = 0.f;
    if (t < NT) {
        float mn = INFINITY, mxv = -INFINITY;
        float Ap = 0.f, Bp = 0.f, An = 0.f, Bn = 0.f;
        for (int cc = 0; cc < CHUNKS; ++cc) {
            const float* p6 = part6 + (size_t)(t * CHUNKS + cc) * 6;
            mn  = fminf(mn,  p6[0]);
            mxv = fmaxf(mxv, p6[1]);
            Ap += p6[2]; Bp += p6[3]; An += p6[4]; Bn += p6[5];
        }
        const float inv = 1.0f / (mxv - mn);
        pos = Ap - inv * (Bp - mn * Ap);
        neg = An - inv * (Bn - mn * An);
    }
    sp[t] = pos; sn[t] = neg;
    __syncthreads();
    if (t == 0) {
        float P = 0.f, N = 0.f;
        for (int i = 0; i < NT; ++i) { P += sp[i]; N += sn[i]; }
        const float total = (P * 0.7f + N * 0.3f) * 2.0f;
        const int e = *epoch;
        const float la = (e < 100) ? (float)e : 100.0f;
        *out = la * total;
    }
}

extern "C" void kernel_launch(void* const* d_in, const int* in_sizes, int n_in,
                              void* d_out, int out_size, void* d_ws, size_t ws_size,
                              hipStream_t stream)
{
    (void)in_sizes; (void)n_in; (void)out_size; (void)ws_size;
    const float* beta  = (const float*)d_in[0];
    const float* W     = (const float*)d_in[1];
    const int*   epoch = (const int*)d_in[2];
    float* out = (float*)d_out;

    char* ws = (char*)d_ws;
    int*   top_idx  = (int*)ws;    ws += NT * TOPN * sizeof(int);
    float* top_p    = (float*)ws;  ws += NT * TOPN * sizeof(float);
    float* rowstats = (float*)ws;  ws += NT * 2 * sizeof(float);
    float* part6    = (float*)ws;  ws += NB * 6 * sizeof(float);

    topk_kernel<<<NT, 256, 0, stream>>>(beta, top_idx, top_p, rowstats);
    fused_kernel<<<NB, 256, 0, stream>>>(beta, W, top_idx, top_p, rowstats, part6);
    finalize_kernel<<<1, 128, 0, stream>>>(part6, epoch, out);
}

// Round 16
// 45.879 us; speedup vs baseline: 1.1129x; 1.0263x over previous
//
#include <hip/hip_runtime.h>
#include <math.h>

#define NT 100       // NUM_TOPICS
#define VOCAB 8192
#define TOPN 20
#define NWV 4        // waves per topk block
#define WCOLS 2048   // cols per wave
#define SCAP 256     // wave-private candidate capacity

// ---- node 1: per-topic top-20, all phases wave-local (VERBATIM R15) + zero out ----
__global__ __launch_bounds__(256) void topk_kernel(
    const float* __restrict__ beta,
    int*   __restrict__ top_idx,   // [NT][TOPN]
    float* __restrict__ top_p,     // [NT][TOPN]
    float* __restrict__ rowstats,  // [NT][2] = {rowmax, full sumexp}
    float* __restrict__ out)
{
    const int k = blockIdx.x;
    const int t = threadIdx.x;
    const int wv = t >> 6;          // wave 0..3
    const int lane = t & 63;
    if (k == 0 && t == 0) *out = 0.f;

    __shared__ float cu[NWV * SCAP];        // 4 KB wave-private candidates
    __shared__ int   cid[NWV * SCAP];       // 4 KB
    __shared__ float smaxs[NWV], ssums[NWV];
    __shared__ float pv[NWV * TOPN];        // 80 pre-candidates
    __shared__ int   pid[NWV * TOPN];
    __shared__ float s_winv[TOPN];
    __shared__ int   s_wini[TOPN];
    __shared__ float s_ps, s_rowmax;

    const float* base = beta + (size_t)k * VOCAB + wv * WCOLS;
    float4 r[8];
    float mx = -INFINITY;
#pragma unroll
    for (int i = 0; i < 8; ++i) {
        r[i] = *reinterpret_cast<const float4*>(base + (size_t)(i * 64 + lane) * 4);
        mx = fmaxf(mx, fmaxf(fmaxf(r[i].x, r[i].y), fmaxf(r[i].z, r[i].w)));
    }
#pragma unroll
    for (int off = 32; off >= 1; off >>= 1) mx = fmaxf(mx, __shfl_xor(mx, off));
    const float smax = mx;

    float se = 0.f;
#pragma unroll
    for (int i = 0; i < 8; ++i) {
        se += expf(r[i].x - smax) + expf(r[i].y - smax)
            + expf(r[i].z - smax) + expf(r[i].w - smax);
    }
#pragma unroll
    for (int off = 32; off >= 1; off >>= 1) se += __shfl_xor(se, off);
    const float ssum = se;

    if (lane == 0) { smaxs[wv] = smax; ssums[wv] = ssum; }

    float T = smax - 1.5f;
    for (int g = 0; g < 16; ++g) {
        int c = 0;
#pragma unroll
        for (int i = 0; i < 8; ++i) {
            c += (r[i].x >= T) + (r[i].y >= T) + (r[i].z >= T) + (r[i].w >= T);
        }
#pragma unroll
        for (int off = 32; off >= 1; off >>= 1) c += __shfl_xor(c, off);
        if (c >= TOPN) break;               // wave-uniform decision
        T -= 0.4f;
    }

    int wbase = 0;
#pragma unroll
    for (int i = 0; i < 8; ++i) {
#pragma unroll
        for (int e = 0; e < 4; ++e) {
            const float v = (&r[i].x)[e];
            const bool pr = (v >= T);
            const unsigned long long mask = __ballot(pr);
            const int pre = __popcll(mask & ((1ull << lane) - 1ull));
            if (pr) {
                const int p = wbase + pre;
                if (p < SCAP) {
                    cu[wv * SCAP + p]  = v;
                    cid[wv * SCAP + p] = wv * WCOLS + (i * 64 + lane) * 4 + e;
                }
            }
            wbase += __popcll(mask);        // wave-uniform
        }
    }
    const int n = min(wbase, SCAP);

    for (int it = 0; it < TOPN; ++it) {
        float bv = -INFINITY; int bp = -1;
        for (int p = lane; p < n; p += 64) {
            const float v = cu[wv * SCAP + p];
            if (v > bv) { bv = v; bp = p; }
        }
#pragma unroll
        for (int off = 32; off >= 1; off >>= 1) {
            const float ov = __shfl_down(bv, off);
            const int   op = __shfl_down(bp, off);
            if (ov > bv) { bv = ov; bp = op; }
        }
        bp = __shfl(bp, 0);
        bv = __shfl(bv, 0);
        if (lane == 0) {
            pv[wv * TOPN + it]  = bv;
            pid[wv * TOPN + it] = (bp >= 0) ? cid[wv * SCAP + bp] : 0;
        }
        if (bp >= 0) cu[wv * SCAP + bp] = -INFINITY;
    }
    __syncthreads();

    if (wv == 0) {
        for (int it = 0; it < TOPN; ++it) {
            float bv = -INFINITY; int bp = -1;
            for (int p = lane; p < NWV * TOPN; p += 64) {
                const float v = pv[p];
                if (v > bv) { bv = v; bp = p; }
            }
#pragma unroll
            for (int off = 32; off >= 1; off >>= 1) {
                const float ov = __shfl_down(bv, off);
                const int   op = __shfl_down(bp, off);
                if (ov > bv) { bv = ov; bp = op; }
            }
            bp = __shfl(bp, 0);
            bv = __shfl(bv, 0);
            if (lane == 0) { s_winv[it] = bv; s_wini[it] = pid[bp]; }
            pv[bp] = -INFINITY;
        }
        if (lane == 0) {
            const float rowmax = s_winv[0];
            float ps = 0.f;
#pragma unroll
            for (int j = 0; j < TOPN; ++j) ps += expf(s_winv[j] - rowmax);
            float rs = 0.f;
#pragma unroll
            for (int s = 0; s < NWV; ++s) rs += ssums[s] * expf(smaxs[s] - rowmax);
            s_rowmax = rowmax;
            s_ps = ps;
            rowstats[2 * k + 0] = rowmax;
            rowstats[2 * k + 1] = rs;
        }
    }
    __syncthreads();
    if (t < TOPN) {
        top_idx[k * TOPN + t] = s_wini[t];
        top_p[k * TOPN + t]   = expf(s_winv[t] - s_rowmax) / s_ps;
    }
}

// ---- node 2: fused gather + loss + per-topic finalize (100 x 1024) ----
__global__ __launch_bounds__(1024) void fused_kernel(
    const float* __restrict__ beta,
    const float* __restrict__ W,
    const int*   __restrict__ top_idx,
    const float* __restrict__ top_p,
    const float* __restrict__ rowstats,
    const int*   __restrict__ epoch,
    float* __restrict__ out)
{
    const int k = blockIdx.x;
    const int t = threadIdx.x;

    __shared__ int   cnt[VOCAB];             // 32 KB full-row histogram
    __shared__ int   sIdx[TOPN];
    __shared__ float sP[TOPN];
    __shared__ float sA[16], sB[16], sC[16], sD[16], sE[16], sF[16];

    if (t < TOPN) { sIdx[t] = top_idx[k * TOPN + t]; sP[t] = top_p[k * TOPN + t]; }
#pragma unroll
    for (int i = 0; i < VOCAB / 1024; ++i) cnt[i * 1024 + t] = 0;
    __syncthreads();

    // full-row histogram over all topics' top-20 (2000 entries), minus own topic
#pragma unroll 2
    for (int e = t; e < NT * TOPN; e += 1024) atomicAdd(&cnt[top_idx[e]], 1);
    if (t < TOPN) atomicSub(&cnt[sIdx[t]], 1);

    int   idx_r[TOPN];
    float p_r[TOPN];
#pragma unroll
    for (int j = 0; j < TOPN; ++j) { idx_r[j] = sIdx[j]; p_r[j] = sP[j]; }

    const float rmax = rowstats[2 * k + 0];
    const float rinv = 1.0f / rowstats[2 * k + 1];

    __syncthreads();                         // cnt final

    float mn = INFINITY, mxv = -INFINITY;
    float Apos = 0.f, Bpos = 0.f, Aneg = 0.f, Bneg = 0.f;

#pragma unroll
    for (int seg = 0; seg < 2; ++seg) {      // 2 segments x 1024 thr x float4
        const int col = seg * 4096 + t * 4;

        float4 m = make_float4(0.f, 0.f, 0.f, 0.f);
#pragma unroll
        for (int j = 0; j < TOPN; ++j) {
            const float4 w = *reinterpret_cast<const float4*>(W + (size_t)idx_r[j] * VOCAB + col);
            const float pj = p_r[j];
            m.x += pj * w.x; m.y += pj * w.y; m.z += pj * w.z; m.w += pj * w.w;
        }
        mn  = fminf(mn,  fminf(fminf(m.x, m.y), fminf(m.z, m.w)));
        mxv = fmaxf(mxv, fmaxf(fmaxf(m.x, m.y), fmaxf(m.z, m.w)));

        const float4 bv = *reinterpret_cast<const float4*>(beta + (size_t)k * VOCAB + col);
        float4 w4;
        w4.x = expf(bv.x - rmax) * rinv;  w4.x = 100.f * w4.x * w4.x;
        w4.y = expf(bv.y - rmax) * rinv;  w4.y = 100.f * w4.y * w4.y;
        w4.z = expf(bv.z - rmax) * rinv;  w4.z = 100.f * w4.z * w4.z;
        w4.w = expf(bv.w - rmax) * rinv;  w4.w = 100.f * w4.w * w4.w;

        const int4 c4 = *reinterpret_cast<const int4*>(cnt + col);
        if (c4.x > 0) { Apos += w4.x; Bpos += w4.x * m.x; } else { Aneg += w4.x; Bneg += w4.x * m.x; }
        if (c4.y > 0) { Apos += w4.y; Bpos += w4.y * m.y; } else { Aneg += w4.y; Bneg += w4.y * m.y; }
        if (c4.z > 0) { Apos += w4.z; Bpos += w4.z * m.z; } else { Aneg += w4.z; Bneg += w4.z * m.z; }
        if (c4.w > 0) { Apos += w4.w; Bpos += w4.w * m.w; } else { Aneg += w4.w; Bneg += w4.w * m.w; }
    }

#pragma unroll
    for (int off = 32; off >= 1; off >>= 1) {
        mn   = fminf(mn,  __shfl_down(mn,  off));
        mxv  = fmaxf(mxv, __shfl_down(mxv, off));
        Apos += __shfl_down(Apos, off);
        Bpos += __shfl_down(Bpos, off);
        Aneg += __shfl_down(Aneg, off);
        Bneg += __shfl_down(Bneg, off);
    }
    if ((t & 63) == 0) {
        const int w = t >> 6;
        sA[w] = mn; sB[w] = mxv; sC[w] = Apos; sD[w] = Bpos; sE[w] = Aneg; sF[w] = Bneg;
    }
    __syncthreads();
    if (t == 0) {
        float a = sA[0], b = sB[0], Ap = 0.f, Bp = 0.f, An = 0.f, Bn = 0.f;
#pragma unroll
        for (int w = 0; w < 16; ++w) {
            a  = fminf(a, sA[w]);
            b  = fmaxf(b, sB[w]);
            Ap += sC[w]; Bp += sD[w]; An += sE[w]; Bn += sF[w];
        }
        const float inv = 1.0f / (b - a);
        const float pos = Ap - inv * (Bp - a * Ap);   // sum w*(1-(M-mn)*inv)
        const float neg = An - inv * (Bn - a * An);
        const int e = *epoch;
        const float la = (e < 100) ? (float)e : 100.0f;   // lambda_a_delta = 1
        atomicAdd(out, la * (pos * 0.7f + neg * 0.3f) * 2.0f);
    }
}

extern "C" void kernel_launch(void* const* d_in, const int* in_sizes, int n_in,
                              void* d_out, int out_size, void* d_ws, size_t ws_size,
                              hipStream_t stream)
{
    (void)in_sizes; (void)n_in; (void)out_size; (void)ws_size;
    const float* beta  = (const float*)d_in[0];
    const float* W     = (const float*)d_in[1];
    const int*   epoch = (const int*)d_in[2];
    float* out = (float*)d_out;

    char* ws = (char*)d_ws;
    int*   top_idx  = (int*)ws;    ws += NT * TOPN * sizeof(int);
    float* top_p    = (float*)ws;  ws += NT * TOPN * sizeof(float);
    float* rowstats = (float*)ws;  ws += NT * 2 * sizeof(float);

    topk_kernel<<<NT, 256, 0, stream>>>(beta, top_idx, top_p, rowstats, out);
    fused_kernel<<<NT, 1024, 0, stream>>>(beta, W, top_idx, top_p, rowstats, epoch, out);
}